// Round 1
// baseline (1445.600 us; speedup 1.0000x reference)
//
#include <hip/hip_runtime.h>
#include <stdint.h>
#include <math.h>

#define C_DIM 2048
#define N_DIM 16384
#define L_DIM 512
#define G_NUM 4
#define EPSV 1e-4f

#define CHEB_D 8
#define NSQ 14
#define ALPHA_S 1.55f
#define CB_A 0.50
#define CB_B 1.55

typedef __attribute__((ext_vector_type(8))) short bf16x8;
typedef __attribute__((ext_vector_type(4))) float f32x4;

static __device__ __forceinline__ unsigned short f2bf(float f) {
  union { float f; unsigned int u; } v; v.f = f;
  unsigned int u = v.u;
  unsigned int r = (u + 0x7FFFu + ((u >> 16) & 1u)) >> 16;  // RNE
  return (unsigned short)r;
}
static __device__ __forceinline__ float bf2f(unsigned short h) {
  union { unsigned int u; float f; } v; v.u = ((unsigned int)h) << 16;
  return v.f;
}

// ---------------- K1: row means + split x into bf16 hi/lo ----------------
__global__ __launch_bounds__(256) void k1_mean_split(
    const float* __restrict__ x, unsigned short* __restrict__ hi,
    unsigned short* __restrict__ lo, float* __restrict__ mu) {
  int c = blockIdx.x;
  const float* row = x + (size_t)c * N_DIM;
  unsigned short* hrow = hi + (size_t)c * N_DIM;
  unsigned short* lrow = lo + (size_t)c * N_DIM;
  float s = 0.f;
  for (int i = threadIdx.x * 4; i < N_DIM; i += 1024) {
    float4 v = *(const float4*)(row + i);
    s += (v.x + v.y) + (v.z + v.w);
    unsigned short h0 = f2bf(v.x), h1 = f2bf(v.y), h2 = f2bf(v.z), h3 = f2bf(v.w);
    ushort4 hh; hh.x = h0; hh.y = h1; hh.z = h2; hh.w = h3;
    *(ushort4*)(hrow + i) = hh;
    ushort4 ll;
    ll.x = f2bf(v.x - bf2f(h0)); ll.y = f2bf(v.y - bf2f(h1));
    ll.z = f2bf(v.z - bf2f(h2)); ll.w = f2bf(v.w - bf2f(h3));
    *(ushort4*)(lrow + i) = ll;
  }
#pragma unroll
  for (int off = 32; off > 0; off >>= 1) s += __shfl_down(s, off);
  __shared__ float red[4];
  if ((threadIdx.x & 63) == 0) red[threadIdx.x >> 6] = s;
  __syncthreads();
  if (threadIdx.x == 0) mu[c] = (red[0] + red[1] + red[2] + red[3]) * (1.f / N_DIM);
}

// ---------------- K2: Gram via split-bf16 MFMA, atomic accumulate --------
// grid = 8 k-chunks x 4 groups x 16 tiles(128x128); 4 waves of 64x64
__global__ __launch_bounds__(256) void k2_cov(
    const unsigned short* __restrict__ hi, const unsigned short* __restrict__ lo,
    float* __restrict__ S) {
  int bid = blockIdx.x;
  int kc = bid >> 6; int rem = bid & 63; int g = rem >> 4; int t = rem & 15;
  int ti = t >> 2, tj = t & 3;
  int lane = threadIdx.x & 63, w = threadIdx.x >> 6;
  int wi = w >> 1, wj = w & 1;
  int l15 = lane & 15, lg = lane >> 4;
  int r0 = g * L_DIM + ti * 128 + wi * 64;
  int c0 = g * L_DIM + tj * 128 + wj * 64;
  f32x4 zz = {0.f, 0.f, 0.f, 0.f};
  f32x4 acc[4][4];
#pragma unroll
  for (int a = 0; a < 4; a++)
#pragma unroll
    for (int b = 0; b < 4; b++) acc[a][b] = zz;
  size_t kb = (size_t)kc * 2048 + (size_t)lg * 8;
  for (int k = 0; k < 2048; k += 32) {
    bf16x8 ah[4], al[4], bh[4], bl[4];
#pragma unroll
    for (int a = 0; a < 4; a++) {
      size_t o = (size_t)(r0 + a * 16 + l15) * N_DIM + kb + k;
      ah[a] = *(const bf16x8*)(hi + o);
      al[a] = *(const bf16x8*)(lo + o);
    }
#pragma unroll
    for (int b = 0; b < 4; b++) {
      size_t o = (size_t)(c0 + b * 16 + l15) * N_DIM + kb + k;
      bh[b] = *(const bf16x8*)(hi + o);
      bl[b] = *(const bf16x8*)(lo + o);
    }
#pragma unroll
    for (int a = 0; a < 4; a++)
#pragma unroll
      for (int b = 0; b < 4; b++) {
        acc[a][b] = __builtin_amdgcn_mfma_f32_16x16x32_bf16(ah[a], bh[b], acc[a][b], 0, 0, 0);
        acc[a][b] = __builtin_amdgcn_mfma_f32_16x16x32_bf16(ah[a], bl[b], acc[a][b], 0, 0, 0);
        acc[a][b] = __builtin_amdgcn_mfma_f32_16x16x32_bf16(al[a], bh[b], acc[a][b], 0, 0, 0);
      }
  }
  float* Sg = S + (size_t)g * L_DIM * L_DIM;
#pragma unroll
  for (int a = 0; a < 4; a++) {
    int rl = ti * 128 + wi * 64 + a * 16 + 4 * lg;
#pragma unroll
    for (int b = 0; b < 4; b++) {
      int cl = tj * 128 + wj * 64 + b * 16 + l15;
#pragma unroll
      for (int i = 0; i < 4; i++)
        atomicAdd(&Sg[(size_t)(rl + i) * L_DIM + cl], acc[a][b][i]);
    }
  }
}

// ---------------- K3: assemble C, M=affine(C), B0=aI-C, T0=I, Pacc init --
__global__ __launch_bounds__(256) void k3_assemble(
    float* __restrict__ S, const float* __restrict__ mu, float c0h, float c1,
    float* __restrict__ Pacc,
    unsigned short* __restrict__ Mhi, unsigned short* __restrict__ Mlo,
    unsigned short* __restrict__ B0hi, unsigned short* __restrict__ B0lo,
    unsigned short* __restrict__ T0hi, unsigned short* __restrict__ T0lo,
    float* __restrict__ trc) {
  size_t idx = (size_t)blockIdx.x * 256 + threadIdx.x;
  int g = (int)(idx >> 18); int r = (int)((idx >> 9) & 511); int cc = (int)(idx & 511);
  float diag = (r == cc) ? 1.f : 0.f;
  float s = S[idx] * (1.f / N_DIM) - mu[g * 512 + r] * mu[g * 512 + cc] + diag * EPSV;
  S[idx] = s;
  float m = (2.f * s - diag * (float)(CB_A + CB_B)) * (float)(1.0 / (CB_B - CB_A));
  unsigned short mh = f2bf(m); Mhi[idx] = mh; Mlo[idx] = f2bf(m - bf2f(mh));
  float b0 = diag * ALPHA_S - s;
  unsigned short bh = f2bf(b0); B0hi[idx] = bh; B0lo[idx] = f2bf(b0 - bf2f(bh));
  Pacc[idx] = c0h * diag + c1 * m;
  T0hi[idx] = (r == cc) ? (unsigned short)0x3F80 : (unsigned short)0;
  T0lo[idx] = 0;
  if (r == cc) atomicAdd(&trc[g], b0);
}

// ---------------- K4: batched 512^3 split-bf16 matmul (cheb / squaring) --
// grid = 4 groups x 64 tiles(64x64); waves of 32x32. Operands symmetric ->
// both A and B fragments are contiguous row reads.
__global__ __launch_bounds__(256) void k4_chain(
    const unsigned short* __restrict__ Ahi, const unsigned short* __restrict__ Alo,
    const unsigned short* __restrict__ Bhi, const unsigned short* __restrict__ Blo,
    unsigned short* __restrict__ Dhi, unsigned short* __restrict__ Dlo,
    int mode,  // 0: D = 2*A*B - Tprev; Pacc += coeff*D.   1: D = (A*A)/that^2, trace out
    const unsigned short* __restrict__ Phi, const unsigned short* __restrict__ Plo,
    float coeff, float* __restrict__ Pacc,
    const float* __restrict__ tr_in, float* __restrict__ tr_out) {
  int bid = blockIdx.x;
  int g = bid >> 6; int t = bid & 63; int ti = t >> 3, tj = t & 7;
  int lane = threadIdx.x & 63, w = threadIdx.x >> 6;
  int wi = w >> 1, wj = w & 1;
  int l15 = lane & 15, lg = lane >> 4;
  int r0 = ti * 64 + wi * 32, c0 = tj * 64 + wj * 32;
  size_t gof = (size_t)g * (L_DIM * L_DIM);
  const unsigned short* Ah = Ahi + gof; const unsigned short* Al = Alo + gof;
  const unsigned short* Bh = Bhi + gof; const unsigned short* Bl = Blo + gof;
  f32x4 zz = {0.f, 0.f, 0.f, 0.f};
  f32x4 acc[2][2];
  acc[0][0] = zz; acc[0][1] = zz; acc[1][0] = zz; acc[1][1] = zz;
  for (int k = 0; k < 512; k += 32) {
    int ko = k + lg * 8;
    bf16x8 ah[2], al2[2], bh[2], bl2[2];
#pragma unroll
    for (int a = 0; a < 2; a++) {
      size_t o = (size_t)(r0 + a * 16 + l15) * 512 + ko;
      ah[a] = *(const bf16x8*)(Ah + o); al2[a] = *(const bf16x8*)(Al + o);
    }
#pragma unroll
    for (int b = 0; b < 2; b++) {
      size_t o = (size_t)(c0 + b * 16 + l15) * 512 + ko;
      bh[b] = *(const bf16x8*)(Bh + o); bl2[b] = *(const bf16x8*)(Bl + o);
    }
#pragma unroll
    for (int a = 0; a < 2; a++)
#pragma unroll
      for (int b = 0; b < 2; b++) {
        acc[a][b] = __builtin_amdgcn_mfma_f32_16x16x32_bf16(ah[a], bh[b], acc[a][b], 0, 0, 0);
        acc[a][b] = __builtin_amdgcn_mfma_f32_16x16x32_bf16(ah[a], bl2[b], acc[a][b], 0, 0, 0);
        acc[a][b] = __builtin_amdgcn_mfma_f32_16x16x32_bf16(al2[a], bh[b], acc[a][b], 0, 0, 0);
      }
  }
  float scale = 1.f;
  if (mode == 1) { float th = tr_in[g] * (1.f / 512.f); scale = 1.f / (th * th); }
#pragma unroll
  for (int a = 0; a < 2; a++) {
    int rr = r0 + a * 16 + 4 * lg;
#pragma unroll
    for (int b = 0; b < 2; b++) {
      int cc = c0 + b * 16 + l15;
#pragma unroll
      for (int i = 0; i < 4; i++) {
        size_t di = gof + (size_t)(rr + i) * 512 + cc;
        float d = acc[a][b][i];
        if (mode == 0) {
          d = 2.f * d - (bf2f(Phi[di]) + bf2f(Plo[di]));
          unsigned short dh = f2bf(d);
          Dhi[di] = dh; Dlo[di] = f2bf(d - bf2f(dh));
          Pacc[di] += coeff * d;
        } else {
          d *= scale;
          unsigned short dh = f2bf(d);
          Dhi[di] = dh; Dlo[di] = f2bf(d - bf2f(dh));
          if (rr + i == cc) atomicAdd(&tr_out[g], d);
        }
      }
    }
  }
}

// ---------------- K5: extract v_min + Rayleigh quotient ------------------
__global__ __launch_bounds__(256) void k5_extract(
    const unsigned short* __restrict__ Bhi, const unsigned short* __restrict__ Blo,
    const float* __restrict__ S, float* __restrict__ vbuf, float* __restrict__ smin) {
  int g = blockIdx.x; int tid = threadIdx.x;
  size_t gof = (size_t)g * (512 * 512);
  __shared__ float sv[256]; __shared__ int si[256];
  __shared__ float vrow[512];
  float best = -1e30f; int bj = 0;
  for (int j = tid; j < 512; j += 256) {
    size_t di = gof + (size_t)j * 512 + j;
    float dv = bf2f(Bhi[di]) + bf2f(Blo[di]);
    if (dv > best) { best = dv; bj = j; }
  }
  sv[tid] = best; si[tid] = bj; __syncthreads();
  for (int s2 = 128; s2 > 0; s2 >>= 1) {
    if (tid < s2 && sv[tid + s2] > sv[tid]) { sv[tid] = sv[tid + s2]; si[tid] = si[tid + s2]; }
    __syncthreads();
  }
  int jm = si[0]; __syncthreads();
  float nl = 0.f;
  for (int j = tid; j < 512; j += 256) {
    size_t ri = gof + (size_t)jm * 512 + j;
    float vv = bf2f(Bhi[ri]) + bf2f(Blo[ri]);
    vrow[j] = vv; nl += vv * vv;
  }
  sv[tid] = nl; __syncthreads();
  for (int s2 = 128; s2 > 0; s2 >>= 1) { if (tid < s2) sv[tid] += sv[tid + s2]; __syncthreads(); }
  float inv = rsqrtf(sv[0]); __syncthreads();
  for (int j = tid; j < 512; j += 256) { vrow[j] *= inv; vbuf[g * 512 + j] = vrow[j]; }
  __syncthreads();
  float rloc = 0.f;
  for (int r = tid; r < 512; r += 256) {
    const float* Sr = S + gof + (size_t)r * 512;
    float u = 0.f;
    for (int j = 0; j < 512; j++) u += Sr[j] * vrow[j];
    rloc += u * vrow[r];
  }
  sv[tid] = rloc; __syncthreads();
  for (int s2 = 128; s2 > 0; s2 >>= 1) { if (tid < s2) sv[tid] += sv[tid + s2]; __syncthreads(); }
  if (tid == 0) smin[g] = rsqrtf(sv[0]);
}

// ---------------- K6: W = Pacc - smin*v*v^T (bf16) + Wmu = W.mu ----------
__global__ __launch_bounds__(256) void k6_compose(
    const float* __restrict__ Pacc, const float* __restrict__ vbuf,
    const float* __restrict__ smin, const float* __restrict__ mu,
    unsigned short* __restrict__ Wbf, float* __restrict__ Wmu) {
  int c = blockIdx.x; int g = c >> 9; int r = c & 511;
  float vr = vbuf[g * 512 + r]; float sm = smin[g];
  float accv = 0.f;
  const float* Pr = Pacc + ((size_t)g * 512 + r) * 512;
  for (int j = threadIdx.x; j < 512; j += 256) {
    float wv = Pr[j] - sm * vr * vbuf[g * 512 + j];
    Wbf[(size_t)c * 512 + j] = f2bf(wv);
    accv += wv * mu[g * 512 + j];
  }
#pragma unroll
  for (int off = 32; off > 0; off >>= 1) accv += __shfl_down(accv, off);
  __shared__ float red[4];
  if ((threadIdx.x & 63) == 0) red[threadIdx.x >> 6] = accv;
  __syncthreads();
  if (threadIdx.x == 0) Wmu[c] = red[0] + red[1] + red[2] + red[3];
}

// ---------------- K7: out = (W @ x_bf16 - Wmu) * weight + bias -----------
// grid = 4 g x 4 Mtiles(128) x 64 Ntiles(256); 4 waves of 128x64
__global__ __launch_bounds__(256) void k7_apply(
    const unsigned short* __restrict__ Wbf, const unsigned short* __restrict__ hi,
    const float* __restrict__ Wmu, const float* __restrict__ weight,
    const float* __restrict__ bias, float* __restrict__ out) {
  int bid = blockIdx.x;
  int nt = bid & 63; int mt = (bid >> 6) & 3; int g = bid >> 8;
  int lane = threadIdx.x & 63, w = threadIdx.x >> 6;
  int l15 = lane & 15, lg = lane >> 4;
  int m0 = mt * 128;
  int n0 = nt * 256;
  __shared__ unsigned short ldsB[256][40];  // [n][k] transposed, stride 40 (80B, 16B-aligned)
  f32x4 zz = {0.f, 0.f, 0.f, 0.f};
  f32x4 acc[8][4];
#pragma unroll
  for (int a = 0; a < 8; a++)
#pragma unroll
    for (int b = 0; b < 4; b++) acc[a][b] = zz;
  const unsigned short* Wg = Wbf + ((size_t)g * 512 + m0) * 512;
  const unsigned short* hg = hi + (size_t)g * 512 * N_DIM;
  for (int k = 0; k < 512; k += 32) {
    __syncthreads();
    for (int v = threadIdx.x; v < 1024; v += 256) {
      int kl = v >> 5; int nv = v & 31;
      bf16x8 vv = *(const bf16x8*)(hg + (size_t)(k + kl) * N_DIM + n0 + nv * 8);
#pragma unroll
      for (int e = 0; e < 8; e++) ldsB[nv * 8 + e][kl] = ((unsigned short*)&vv)[e];
    }
    __syncthreads();
    bf16x8 afr[8], bfr[4];
#pragma unroll
    for (int a = 0; a < 8; a++)
      afr[a] = *(const bf16x8*)(Wg + (size_t)(a * 16 + l15) * 512 + k + lg * 8);
#pragma unroll
    for (int b = 0; b < 4; b++)
      bfr[b] = *(const bf16x8*)(&ldsB[w * 64 + b * 16 + l15][lg * 8]);
#pragma unroll
    for (int a = 0; a < 8; a++)
#pragma unroll
      for (int b = 0; b < 4; b++)
        acc[a][b] = __builtin_amdgcn_mfma_f32_16x16x32_bf16(afr[a], bfr[b], acc[a][b], 0, 0, 0);
  }
#pragma unroll
  for (int a = 0; a < 8; a++) {
#pragma unroll
    for (int i = 0; i < 4; i++) {
      int c = g * 512 + m0 + a * 16 + 4 * lg + i;
      float wm = Wmu[c], wt = weight[c], bs = bias[c];
      float* orow = out + (size_t)c * N_DIM + n0 + w * 64;
#pragma unroll
      for (int b = 0; b < 4; b++)
        orow[b * 16 + l15] = (acc[a][b][i] - wm) * wt + bs;
    }
  }
}

extern "C" void kernel_launch(void* const* d_in, const int* in_sizes, int n_in,
                              void* d_out, int out_size, void* d_ws, size_t ws_size,
                              hipStream_t stream) {
  (void)in_sizes; (void)n_in; (void)out_size; (void)ws_size;
  const float* x = (const float*)d_in[0];
  const float* weight = (const float*)d_in[1];
  const float* bias = (const float*)d_in[2];
  float* out = (float*)d_out;

  char* ws = (char*)d_ws;
  size_t off = 0;
  auto alloc = [&](size_t bytes) -> char* {
    char* p = ws + off; off += (bytes + 255) & ~(size_t)255; return p;
  };
  const size_t MAT = (size_t)G_NUM * L_DIM * L_DIM;  // elements per matrix set
  unsigned short* hi  = (unsigned short*)alloc((size_t)C_DIM * N_DIM * 2);  // 64MB
  float* S            = (float*)alloc(MAT * 4);
  float* Pacc         = (float*)alloc(MAT * 4);
  unsigned short* Mhi = (unsigned short*)alloc(MAT * 2);
  unsigned short* Mlo = (unsigned short*)alloc(MAT * 2);
  unsigned short* B0hi= (unsigned short*)alloc(MAT * 2);
  unsigned short* B0lo= (unsigned short*)alloc(MAT * 2);
  unsigned short* T0hi= (unsigned short*)alloc(MAT * 2);
  unsigned short* T0lo= (unsigned short*)alloc(MAT * 2);
  unsigned short* TAhi= (unsigned short*)alloc(MAT * 2);
  unsigned short* TAlo= (unsigned short*)alloc(MAT * 2);
  unsigned short* TBhi= (unsigned short*)alloc(MAT * 2);
  unsigned short* TBlo= (unsigned short*)alloc(MAT * 2);
  unsigned short* Wbf = (unsigned short*)alloc(MAT * 2);
  float* mu   = (float*)alloc(C_DIM * 4);
  float* trc  = (float*)alloc(64 * 4);
  float* vbuf = (float*)alloc(G_NUM * L_DIM * 4);
  float* smin = (float*)alloc(16);
  float* Wmu  = (float*)alloc(C_DIM * 4);
  // lo plane of x lives in d_out: dead before k7 overwrites every element.
  unsigned short* lo = (unsigned short*)d_out;

  // Chebyshev coefficients of 1/sqrt(x) on [CB_A, CB_B] (host, double).
  double cc[CHEB_D + 1];
  for (int k = 0; k <= CHEB_D; k++) cc[k] = 0.0;
  const int mq = 256;
  for (int j = 0; j < mq; j++) {
    double th = M_PI * (j + 0.5) / mq;
    double xx = 0.5 * (CB_B + CB_A) + 0.5 * (CB_B - CB_A) * cos(th);
    double fv = 1.0 / sqrt(xx);
    for (int k = 0; k <= CHEB_D; k++) cc[k] += (2.0 / mq) * fv * cos(k * th);
  }

  hipMemsetAsync(S, 0, MAT * 4, stream);
  hipMemsetAsync(trc, 0, 64 * 4, stream);

  k1_mean_split<<<2048, 256, 0, stream>>>(x, hi, lo, mu);
  k2_cov<<<512, 256, 0, stream>>>(hi, lo, S);
  k3_assemble<<<4096, 256, 0, stream>>>(S, mu, (float)(cc[0] * 0.5), (float)cc[1],
                                        Pacc, Mhi, Mlo, B0hi, B0lo, T0hi, T0lo, trc);

  // Chebyshev recurrence: T_{k+1} = 2 M T_k - T_{k-1}; Pacc += c_{k+1} T_{k+1}
  // slot rotation over {T0,TA,TB}; T1 = M.
  {
    struct Step { const unsigned short *bh, *bl, *ph, *pl; unsigned short *dh, *dl; float cf; };
    Step st[7] = {
      { Mhi,  Mlo,  T0hi, T0lo, TAhi, TAlo, (float)cc[2] },
      { TAhi, TAlo, Mhi,  Mlo,  TBhi, TBlo, (float)cc[3] },
      { TBhi, TBlo, TAhi, TAlo, T0hi, T0lo, (float)cc[4] },
      { T0hi, T0lo, TBhi, TBlo, TAhi, TAlo, (float)cc[5] },
      { TAhi, TAlo, T0hi, T0lo, TBhi, TBlo, (float)cc[6] },
      { TBhi, TBlo, TAhi, TAlo, T0hi, T0lo, (float)cc[7] },
      { T0hi, T0lo, TBhi, TBlo, TAhi, TAlo, (float)cc[8] },
    };
    for (int i = 0; i < 7; i++)
      k4_chain<<<256, 256, 0, stream>>>(Mhi, Mlo, st[i].bh, st[i].bl, st[i].dh, st[i].dl,
                                        0, st[i].ph, st[i].pl, st[i].cf, Pacc,
                                        (const float*)nullptr, (float*)nullptr);
  }

  // Repeated squaring of B0 = ALPHA*I - S with trace normalization.
  {
    const unsigned short* inh = B0hi; const unsigned short* inl = B0lo;
    for (int s = 0; s < NSQ; s++) {
      unsigned short* oh = (s % 2 == 0) ? TAhi : TBhi;
      unsigned short* ol = (s % 2 == 0) ? TAlo : TBlo;
      k4_chain<<<256, 256, 0, stream>>>(inh, inl, inh, inl, oh, ol,
                                        1, (const unsigned short*)nullptr,
                                        (const unsigned short*)nullptr, 0.f, (float*)nullptr,
                                        trc + (size_t)s * 4, trc + (size_t)(s + 1) * 4);
      inh = oh; inl = ol;
    }
    k5_extract<<<4, 256, 0, stream>>>(inh, inl, S, vbuf, smin);
  }

  k6_compose<<<2048, 256, 0, stream>>>(Pacc, vbuf, smin, mu, Wbf, Wmu);
  k7_apply<<<1024, 256, 0, stream>>>(Wbf, hi, Wmu, weight, bias, out);
}

// Round 4
// 1157.051 us; speedup vs baseline: 1.2494x; 1.2494x over previous
//
#include <hip/hip_runtime.h>
#include <stdint.h>
#include <math.h>

#define C_DIM 2048
#define N_DIM 16384
#define L_DIM 512
#define G_NUM 4
#define EPSV 1e-4f

#define CHEB_D 8
#define NSQ 13
#define ALPHA_S 1.55f
#define CB_A 0.50
#define CB_B 1.55

typedef __attribute__((ext_vector_type(8))) short bf16x8;
typedef __attribute__((ext_vector_type(4))) float f32x4;

static __device__ __forceinline__ unsigned short f2bf(float f) {
  union { float f; unsigned int u; } v; v.f = f;
  unsigned int u = v.u;
  unsigned int r = (u + 0x7FFFu + ((u >> 16) & 1u)) >> 16;  // RNE
  return (unsigned short)r;
}
static __device__ __forceinline__ float bf2f(unsigned short h) {
  union { unsigned int u; float f; } v; v.u = ((unsigned int)h) << 16;
  return v.f;
}

// ---------------- K1: row means + split x into bf16 hi/lo ----------------
__global__ __launch_bounds__(256) void k1_mean_split(
    const float* __restrict__ x, unsigned short* __restrict__ hi,
    unsigned short* __restrict__ lo, float* __restrict__ mu) {
  int c = blockIdx.x;
  const float* row = x + (size_t)c * N_DIM;
  unsigned short* hrow = hi + (size_t)c * N_DIM;
  unsigned short* lrow = lo + (size_t)c * N_DIM;
  float s = 0.f;
  for (int i = threadIdx.x * 4; i < N_DIM; i += 1024) {
    float4 v = *(const float4*)(row + i);
    s += (v.x + v.y) + (v.z + v.w);
    unsigned short h0 = f2bf(v.x), h1 = f2bf(v.y), h2 = f2bf(v.z), h3 = f2bf(v.w);
    ushort4 hh; hh.x = h0; hh.y = h1; hh.z = h2; hh.w = h3;
    *(ushort4*)(hrow + i) = hh;
    ushort4 ll;
    ll.x = f2bf(v.x - bf2f(h0)); ll.y = f2bf(v.y - bf2f(h1));
    ll.z = f2bf(v.z - bf2f(h2)); ll.w = f2bf(v.w - bf2f(h3));
    *(ushort4*)(lrow + i) = ll;
  }
#pragma unroll
  for (int off = 32; off > 0; off >>= 1) s += __shfl_down(s, off);
  __shared__ float red[4];
  if ((threadIdx.x & 63) == 0) red[threadIdx.x >> 6] = s;
  __syncthreads();
  if (threadIdx.x == 0) mu[c] = (red[0] + red[1] + red[2] + red[3]) * (1.f / N_DIM);
}

// ---------------- K2: Gram via split-bf16 MFMA, upper-triangle tiles -----
// grid = 8 k-chunks x 4 groups x 10 tiles(128x128, ti<=tj); 4 waves of 64x64
__global__ __launch_bounds__(256) void k2_cov(
    const unsigned short* __restrict__ hi, const unsigned short* __restrict__ lo,
    float* __restrict__ S) {
  const int TI[10] = {0,0,0,0,1,1,1,2,2,3};
  const int TJ[10] = {0,1,2,3,1,2,3,2,3,3};
  int bid = blockIdx.x;
  int t = bid % 10; int g = (bid / 10) & 3; int kc = bid / 40;
  int ti = TI[t], tj = TJ[t];
  int lane = threadIdx.x & 63, w = threadIdx.x >> 6;
  int wi = w >> 1, wj = w & 1;
  int l15 = lane & 15, lg = lane >> 4;
  int r0 = g * L_DIM + ti * 128 + wi * 64;
  int c0 = g * L_DIM + tj * 128 + wj * 64;
  f32x4 zz = {0.f, 0.f, 0.f, 0.f};
  f32x4 acc[4][4];
#pragma unroll
  for (int a = 0; a < 4; a++)
#pragma unroll
    for (int b = 0; b < 4; b++) acc[a][b] = zz;
  size_t kb = (size_t)kc * 2048 + (size_t)lg * 8;
  for (int k = 0; k < 2048; k += 32) {
    bf16x8 ah[4], al[4], bh[4], bl[4];
#pragma unroll
    for (int a = 0; a < 4; a++) {
      size_t o = (size_t)(r0 + a * 16 + l15) * N_DIM + kb + k;
      ah[a] = *(const bf16x8*)(hi + o);
      al[a] = *(const bf16x8*)(lo + o);
    }
#pragma unroll
    for (int b = 0; b < 4; b++) {
      size_t o = (size_t)(c0 + b * 16 + l15) * N_DIM + kb + k;
      bh[b] = *(const bf16x8*)(hi + o);
      bl[b] = *(const bf16x8*)(lo + o);
    }
#pragma unroll
    for (int a = 0; a < 4; a++)
#pragma unroll
      for (int b = 0; b < 4; b++) {
        acc[a][b] = __builtin_amdgcn_mfma_f32_16x16x32_bf16(ah[a], bh[b], acc[a][b], 0, 0, 0);
        acc[a][b] = __builtin_amdgcn_mfma_f32_16x16x32_bf16(ah[a], bl[b], acc[a][b], 0, 0, 0);
        acc[a][b] = __builtin_amdgcn_mfma_f32_16x16x32_bf16(al[a], bh[b], acc[a][b], 0, 0, 0);
      }
  }
  float* Sg = S + (size_t)g * L_DIM * L_DIM;
#pragma unroll
  for (int a = 0; a < 4; a++) {
    int rl = ti * 128 + wi * 64 + a * 16 + 4 * lg;
#pragma unroll
    for (int b = 0; b < 4; b++) {
      int cl = tj * 128 + wj * 64 + b * 16 + l15;
#pragma unroll
      for (int i = 0; i < 4; i++)
        atomicAdd(&Sg[(size_t)(rl + i) * L_DIM + cl], acc[a][b][i]);
    }
  }
}

// ---------------- T1: x (fp32) -> hiT bf16 [n][c], tiled transpose -------
// writes into the (now dead) hi buffer reinterpreted as [16384][2048]
__global__ __launch_bounds__(256) void t1_transpose(
    const float* __restrict__ x, unsigned short* __restrict__ hiT) {
  __shared__ unsigned short tile[64][72];  // pitch 72 ushort = 144B (16B aligned rows)
  int bid = blockIdx.x;
  int ct = bid >> 8;       // 2048/64 = 32 c-tiles
  int nt = bid & 255;      // 16384/64 = 256 n-tiles
  int c0 = ct * 64, n0 = nt * 64;
  int t = threadIdx.x;
  {
    int r = t >> 2;              // c-local 0..63
    int cc = (t & 3) * 16;       // n-local chunk
    const float* xp = x + (size_t)(c0 + r) * N_DIM + n0 + cc;
    float4 v0 = *(const float4*)(xp + 0);
    float4 v1 = *(const float4*)(xp + 4);
    float4 v2 = *(const float4*)(xp + 8);
    float4 v3 = *(const float4*)(xp + 12);
    bf16x8 p0, p1;
    ((unsigned short*)&p0)[0] = f2bf(v0.x); ((unsigned short*)&p0)[1] = f2bf(v0.y);
    ((unsigned short*)&p0)[2] = f2bf(v0.z); ((unsigned short*)&p0)[3] = f2bf(v0.w);
    ((unsigned short*)&p0)[4] = f2bf(v1.x); ((unsigned short*)&p0)[5] = f2bf(v1.y);
    ((unsigned short*)&p0)[6] = f2bf(v1.z); ((unsigned short*)&p0)[7] = f2bf(v1.w);
    ((unsigned short*)&p1)[0] = f2bf(v2.x); ((unsigned short*)&p1)[1] = f2bf(v2.y);
    ((unsigned short*)&p1)[2] = f2bf(v2.z); ((unsigned short*)&p1)[3] = f2bf(v2.w);
    ((unsigned short*)&p1)[4] = f2bf(v3.x); ((unsigned short*)&p1)[5] = f2bf(v3.y);
    ((unsigned short*)&p1)[6] = f2bf(v3.z); ((unsigned short*)&p1)[7] = f2bf(v3.w);
    *(bf16x8*)&tile[r][cc] = p0;
    *(bf16x8*)&tile[r][cc + 8] = p1;
  }
  __syncthreads();
  {
    int n = t >> 2;              // n-local 0..63
    int ck = (t & 3) * 16;       // c-local chunk
    bf16x8 o0, o1;
#pragma unroll
    for (int i = 0; i < 8; i++) ((unsigned short*)&o0)[i] = tile[ck + i][n];
#pragma unroll
    for (int i = 0; i < 8; i++) ((unsigned short*)&o1)[i] = tile[ck + 8 + i][n];
    unsigned short* op = hiT + (size_t)(n0 + n) * C_DIM + c0 + ck;
    *(bf16x8*)(op) = o0;
    *(bf16x8*)(op + 8) = o1;
  }
}

// ---------------- K3: Scov, M=affine(C), B0=aI-C, T0=I, Pacc init --------
__global__ __launch_bounds__(256) void k3_assemble(
    const float* __restrict__ Sraw, float* __restrict__ Scov,
    const float* __restrict__ mu, float c0h, float c1,
    float* __restrict__ Pacc,
    unsigned short* __restrict__ Mhi, unsigned short* __restrict__ Mlo,
    unsigned short* __restrict__ B0hi, unsigned short* __restrict__ B0lo,
    unsigned short* __restrict__ T0hi, unsigned short* __restrict__ T0lo,
    float* __restrict__ trc) {
  size_t idx = (size_t)blockIdx.x * 256 + threadIdx.x;
  int g = (int)(idx >> 18); int r = (int)((idx >> 9) & 511); int cc = (int)(idx & 511);
  int rl = r <= cc ? r : cc, ch = r <= cc ? cc : r;
  float diag = (r == cc) ? 1.f : 0.f;
  float raw = Sraw[((size_t)g << 18) + ((size_t)rl << 9) + ch];
  float s = raw * (1.f / N_DIM) - mu[g * 512 + r] * mu[g * 512 + cc] + diag * EPSV;
  Scov[idx] = s;
  float m = (2.f * s - diag * (float)(CB_A + CB_B)) * (float)(1.0 / (CB_B - CB_A));
  unsigned short mh = f2bf(m); Mhi[idx] = mh; Mlo[idx] = f2bf(m - bf2f(mh));
  float b0 = diag * ALPHA_S - s;
  unsigned short bh = f2bf(b0); B0hi[idx] = bh; B0lo[idx] = f2bf(b0 - bf2f(bh));
  Pacc[idx] = c0h * diag + c1 * m;
  T0hi[idx] = (r == cc) ? (unsigned short)0x3F80 : (unsigned short)0;
  T0lo[idx] = 0;
  if (r == cc) atomicAdd(&trc[g], b0);
}

// ---------------- K4F: fused batched 512^3 split-bf16 matmuls ------------
// blocks [0, cheb_blocks): D = 2*M*B - P; Pacc += coeff*D
// blocks [cheb_blocks, +256): E = (Q*Q)/theta^2, trace out
__global__ __launch_bounds__(256) void k4_fused(
    int cheb_blocks,
    const unsigned short* __restrict__ Mh, const unsigned short* __restrict__ Ml,
    const unsigned short* __restrict__ Bh, const unsigned short* __restrict__ Bl,
    const unsigned short* __restrict__ Ph, const unsigned short* __restrict__ Pl,
    unsigned short* __restrict__ Dh, unsigned short* __restrict__ Dl,
    float coeff, float* __restrict__ Pacc,
    const unsigned short* __restrict__ Qh, const unsigned short* __restrict__ Ql,
    unsigned short* __restrict__ Eh, unsigned short* __restrict__ El,
    const float* __restrict__ tr_in, float* __restrict__ tr_out) {
  int bid = blockIdx.x;
  bool sqr = bid >= cheb_blocks;
  int t6 = sqr ? bid - cheb_blocks : bid;
  int g = t6 >> 6; int t = t6 & 63; int ti = t >> 3, tj = t & 7;
  int lane = threadIdx.x & 63, w = threadIdx.x >> 6;
  int wi = w >> 1, wj = w & 1;
  int l15 = lane & 15, lg = lane >> 4;
  int r0 = ti * 64 + wi * 32, c0 = tj * 64 + wj * 32;
  size_t gof = (size_t)g * (L_DIM * L_DIM);
  const unsigned short* Ah_ = (sqr ? Qh : Mh) + gof;
  const unsigned short* Al_ = (sqr ? Ql : Ml) + gof;
  const unsigned short* Bh_ = (sqr ? Qh : Bh) + gof;
  const unsigned short* Bl_ = (sqr ? Ql : Bl) + gof;
  f32x4 zz = {0.f, 0.f, 0.f, 0.f};
  f32x4 acc[2][2];
  acc[0][0] = zz; acc[0][1] = zz; acc[1][0] = zz; acc[1][1] = zz;
  for (int k = 0; k < 512; k += 32) {
    int ko = k + lg * 8;
    bf16x8 ah[2], al2[2], bh2[2], bl2[2];
#pragma unroll
    for (int a = 0; a < 2; a++) {
      size_t o = (size_t)(r0 + a * 16 + l15) * 512 + ko;
      ah[a] = *(const bf16x8*)(Ah_ + o); al2[a] = *(const bf16x8*)(Al_ + o);
    }
#pragma unroll
    for (int b = 0; b < 2; b++) {
      size_t o = (size_t)(c0 + b * 16 + l15) * 512 + ko;
      bh2[b] = *(const bf16x8*)(Bh_ + o); bl2[b] = *(const bf16x8*)(Bl_ + o);
    }
#pragma unroll
    for (int a = 0; a < 2; a++)
#pragma unroll
      for (int b = 0; b < 2; b++) {
        acc[a][b] = __builtin_amdgcn_mfma_f32_16x16x32_bf16(ah[a], bh2[b], acc[a][b], 0, 0, 0);
        acc[a][b] = __builtin_amdgcn_mfma_f32_16x16x32_bf16(ah[a], bl2[b], acc[a][b], 0, 0, 0);
        acc[a][b] = __builtin_amdgcn_mfma_f32_16x16x32_bf16(al2[a], bh2[b], acc[a][b], 0, 0, 0);
      }
  }
  float scale = 1.f;
  if (sqr) { float th = tr_in[g] * (1.f / 512.f); scale = 1.f / (th * th); }
#pragma unroll
  for (int a = 0; a < 2; a++) {
    int rr = r0 + a * 16 + 4 * lg;
#pragma unroll
    for (int b = 0; b < 2; b++) {
      int cc = c0 + b * 16 + l15;
#pragma unroll
      for (int i = 0; i < 4; i++) {
        size_t di = gof + (size_t)(rr + i) * 512 + cc;
        float d = acc[a][b][i];
        if (!sqr) {
          d = 2.f * d - (bf2f(Ph[di]) + bf2f(Pl[di]));
          unsigned short dh = f2bf(d);
          Dh[di] = dh; Dl[di] = f2bf(d - bf2f(dh));
          Pacc[di] += coeff * d;
        } else {
          d *= scale;
          unsigned short dh = f2bf(d);
          Eh[di] = dh; El[di] = f2bf(d - bf2f(dh));
          if (rr + i == cc) atomicAdd(&tr_out[g], d);
        }
      }
    }
  }
}

// ---------------- K5a: extract v_min from the squared chain --------------
__global__ __launch_bounds__(256) void k5a_extract(
    const unsigned short* __restrict__ Bhi, const unsigned short* __restrict__ Blo,
    float* __restrict__ vbuf) {
  int g = blockIdx.x; int tid = threadIdx.x;
  size_t gof = (size_t)g * (512 * 512);
  __shared__ float sv[256]; __shared__ int si[256];
  float best = -1e30f; int bj = 0;
  for (int j = tid; j < 512; j += 256) {
    size_t di = gof + (size_t)j * 512 + j;
    float dv = bf2f(Bhi[di]) + bf2f(Blo[di]);
    if (dv > best) { best = dv; bj = j; }
  }
  sv[tid] = best; si[tid] = bj; __syncthreads();
  for (int s2 = 128; s2 > 0; s2 >>= 1) {
    if (tid < s2 && sv[tid + s2] > sv[tid]) { sv[tid] = sv[tid + s2]; si[tid] = si[tid + s2]; }
    __syncthreads();
  }
  int jm = si[0]; __syncthreads();
  float nl = 0.f;
  __shared__ float vrow[512];
  for (int j = tid; j < 512; j += 256) {
    size_t ri = gof + (size_t)jm * 512 + j;
    float vv = bf2f(Bhi[ri]) + bf2f(Blo[ri]);
    vrow[j] = vv; nl += vv * vv;
  }
  sv[tid] = nl; __syncthreads();
  for (int s2 = 128; s2 > 0; s2 >>= 1) { if (tid < s2) sv[tid] += sv[tid + s2]; __syncthreads(); }
  float inv = rsqrtf(sv[0]);
  for (int j = tid; j < 512; j += 256) vbuf[g * 512 + j] = vrow[j] * inv;
}

// ---------------- K5b: dot[g] = v^T Scov v (Rayleigh) --------------------
__global__ __launch_bounds__(256) void k5b_rayleigh(
    const float* __restrict__ Scov, const float* __restrict__ vbuf,
    float* __restrict__ dot) {
  int bid = blockIdx.x; int g = bid >> 4; int r0 = (bid & 15) * 32;
  int t = threadIdx.x;
  int r = r0 + (t >> 3); int c0 = (t & 7) * 64;
  const float* Sr = Scov + ((size_t)g * 512 + r) * 512 + c0;
  const float* vg = vbuf + g * 512;
  float s = 0.f;
#pragma unroll
  for (int j = 0; j < 64; j += 4) {
    float4 sv = *(const float4*)(Sr + j);
    s += sv.x * vg[c0 + j] + sv.y * vg[c0 + j + 1] + sv.z * vg[c0 + j + 2] + sv.w * vg[c0 + j + 3];
  }
  s += __shfl_xor(s, 1); s += __shfl_xor(s, 2); s += __shfl_xor(s, 4);
  if ((t & 7) == 0) atomicAdd(&dot[g], s * vg[r]);
}

// ---------------- K6: W' = weight*(Pacc - rsqrt(dot) v v^T); off = b - W'mu
__global__ __launch_bounds__(256) void k6_compose(
    const float* __restrict__ Pacc, const float* __restrict__ vbuf,
    const float* __restrict__ dot, const float* __restrict__ mu,
    const float* __restrict__ weight, const float* __restrict__ bias,
    unsigned short* __restrict__ Wbf, float* __restrict__ off) {
  int c = blockIdx.x; int g = c >> 9; int r = c & 511;
  float vr = vbuf[g * 512 + r]; float sm = rsqrtf(dot[g]);
  float wt = weight[c];
  float accv = 0.f;
  const float* Pr = Pacc + ((size_t)g * 512 + r) * 512;
  for (int j = threadIdx.x; j < 512; j += 256) {
    float wv = (Pr[j] - sm * vr * vbuf[g * 512 + j]) * wt;
    Wbf[(size_t)c * 512 + j] = f2bf(wv);
    accv += wv * mu[g * 512 + j];
  }
#pragma unroll
  for (int o2 = 32; o2 > 0; o2 >>= 1) accv += __shfl_down(accv, o2);
  __shared__ float red[4];
  if ((threadIdx.x & 63) == 0) red[threadIdx.x >> 6] = accv;
  __syncthreads();
  if (threadIdx.x == 0) off[c] = bias[c] - (red[0] + red[1] + red[2] + red[3]);
}

// ---------------- K7: out = W' @ x + off  (no LDS, direct-global MFMA) ---
// grid 2048 = 4g x 128nt x 4mt (mt minor) with bijective XCD swizzle
__global__ __launch_bounds__(256) void k7_apply(
    const unsigned short* __restrict__ Wbf, const unsigned short* __restrict__ hiT,
    const float* __restrict__ off, float* __restrict__ out) {
  int bid0 = blockIdx.x;
  int bid = (bid0 & 7) * 256 + (bid0 >> 3);
  int mt = bid & 3; int nt = (bid >> 2) & 127; int g = bid >> 9;
  int lane = threadIdx.x & 63, w = threadIdx.x >> 6;
  int wi = w >> 1, wj = w & 1;
  int l15 = lane & 15, lg = lane >> 4;
  int mbase = mt * 128 + wi * 64;        // within-group channel row
  int nbase = nt * 128 + wj * 64;        // global col
  const unsigned short* Wg = Wbf + (size_t)(g * 512 + mbase) * 512;
  const unsigned short* Hg = hiT + (size_t)nbase * C_DIM + g * 512;
  f32x4 zz = {0.f, 0.f, 0.f, 0.f};
  f32x4 acc[4][4];
#pragma unroll
  for (int a = 0; a < 4; a++)
#pragma unroll
    for (int b = 0; b < 4; b++) acc[a][b] = zz;
  for (int k = 0; k < 512; k += 32) {
    int ko = k + lg * 8;
    bf16x8 af[4], bf[4];
#pragma unroll
    for (int a = 0; a < 4; a++)
      af[a] = *(const bf16x8*)(Wg + (size_t)(a * 16 + l15) * 512 + ko);
#pragma unroll
    for (int b = 0; b < 4; b++)
      bf[b] = *(const bf16x8*)(Hg + (size_t)(b * 16 + l15) * C_DIM + ko);
#pragma unroll
    for (int a = 0; a < 4; a++)
#pragma unroll
      for (int b = 0; b < 4; b++)
        acc[a][b] = __builtin_amdgcn_mfma_f32_16x16x32_bf16(af[a], bf[b], acc[a][b], 0, 0, 0);
  }
#pragma unroll
  for (int a = 0; a < 4; a++) {
#pragma unroll
    for (int i = 0; i < 4; i++) {
      int c = g * 512 + mbase + a * 16 + 4 * lg + i;
      float ofc = off[c];
      float* orow = out + (size_t)c * N_DIM + nbase;
#pragma unroll
      for (int b = 0; b < 4; b++)
        orow[b * 16 + l15] = acc[a][b][i] + ofc;
    }
  }
}

extern "C" void kernel_launch(void* const* d_in, const int* in_sizes, int n_in,
                              void* d_out, int out_size, void* d_ws, size_t ws_size,
                              hipStream_t stream) {
  (void)in_sizes; (void)n_in; (void)out_size; (void)ws_size;
  const float* x = (const float*)d_in[0];
  const float* weight = (const float*)d_in[1];
  const float* bias = (const float*)d_in[2];
  float* out = (float*)d_out;

  char* ws = (char*)d_ws;
  size_t off_b = 0;
  auto alloc = [&](size_t bytes) -> char* {
    char* p = ws + off_b; off_b += (bytes + 255) & ~(size_t)255; return p;
  };
  const size_t MAT = (size_t)G_NUM * L_DIM * L_DIM;
  unsigned short* hi  = (unsigned short*)alloc((size_t)C_DIM * N_DIM * 2);  // 64MB; becomes hiT
  float* Sraw         = (float*)alloc(MAT * 4);
  float* Scov         = (float*)alloc(MAT * 4);
  float* Pacc         = (float*)alloc(MAT * 4);
  unsigned short* Mhi = (unsigned short*)alloc(MAT * 2);
  unsigned short* Mlo = (unsigned short*)alloc(MAT * 2);
  unsigned short* B0hi= (unsigned short*)alloc(MAT * 2);
  unsigned short* B0lo= (unsigned short*)alloc(MAT * 2);
  unsigned short* T0hi= (unsigned short*)alloc(MAT * 2);
  unsigned short* T0lo= (unsigned short*)alloc(MAT * 2);
  unsigned short* TAhi= (unsigned short*)alloc(MAT * 2);
  unsigned short* TAlo= (unsigned short*)alloc(MAT * 2);
  unsigned short* TBhi= (unsigned short*)alloc(MAT * 2);
  unsigned short* TBlo= (unsigned short*)alloc(MAT * 2);
  unsigned short* SAhi= (unsigned short*)alloc(MAT * 2);
  unsigned short* SAlo= (unsigned short*)alloc(MAT * 2);
  unsigned short* SBhi= (unsigned short*)alloc(MAT * 2);
  unsigned short* SBlo= (unsigned short*)alloc(MAT * 2);
  unsigned short* Wbf = (unsigned short*)alloc(MAT * 2);
  float* mu   = (float*)alloc(C_DIM * 4);
  float* trc  = (float*)alloc(64 * 4);   // trace chain [0..55], dot at [56..59]
  float* vbuf = (float*)alloc(G_NUM * L_DIM * 4);
  float* offv = (float*)alloc(C_DIM * 4);
  float* dot  = trc + 56;
  // lo plane of x lives in d_out: dead before k7 overwrites every element.
  unsigned short* lo = (unsigned short*)d_out;

  // Chebyshev coefficients of 1/sqrt(x) on [CB_A, CB_B] (host, double).
  double cc[CHEB_D + 1];
  for (int k = 0; k <= CHEB_D; k++) cc[k] = 0.0;
  const int mq = 256;
  for (int j = 0; j < mq; j++) {
    double th = M_PI * (j + 0.5) / mq;
    double xx = 0.5 * (CB_B + CB_A) + 0.5 * (CB_B - CB_A) * cos(th);
    double fv = 1.0 / sqrt(xx);
    for (int k = 0; k <= CHEB_D; k++) cc[k] += (2.0 / mq) * fv * cos(k * th);
  }

  hipMemsetAsync(Sraw, 0, MAT * 4, stream);
  hipMemsetAsync(trc, 0, 64 * 4, stream);

  k1_mean_split<<<2048, 256, 0, stream>>>(x, hi, lo, mu);
  k2_cov<<<320, 256, 0, stream>>>(hi, lo, Sraw);
  // hi is now dead as [c][n]; overwrite with transposed bf16 of x.
  t1_transpose<<<8192, 256, 0, stream>>>(x, hi);
  k3_assemble<<<4096, 256, 0, stream>>>(Sraw, Scov, mu, (float)(cc[0] * 0.5), (float)cc[1],
                                        Pacc, Mhi, Mlo, B0hi, B0lo, T0hi, T0lo, trc);

  // Fused chains: Chebyshev recurrence (7 steps) || repeated squaring (13 steps).
  {
    struct Step { const unsigned short *bh, *bl, *ph, *pl; unsigned short *dh, *dl; float cf; };
    Step st[7] = {
      { Mhi,  Mlo,  T0hi, T0lo, TAhi, TAlo, (float)cc[2] },
      { TAhi, TAlo, Mhi,  Mlo,  TBhi, TBlo, (float)cc[3] },
      { TBhi, TBlo, TAhi, TAlo, T0hi, T0lo, (float)cc[4] },
      { T0hi, T0lo, TBhi, TBlo, TAhi, TAlo, (float)cc[5] },
      { TAhi, TAlo, T0hi, T0lo, TBhi, TBlo, (float)cc[6] },
      { TBhi, TBlo, TAhi, TAlo, T0hi, T0lo, (float)cc[7] },
      { T0hi, T0lo, TBhi, TBlo, TAhi, TAlo, (float)cc[8] },
    };
    const unsigned short* qh = B0hi; const unsigned short* ql = B0lo;
    for (int s = 0; s < NSQ; s++) {
      unsigned short* eh = (s % 2 == 0) ? SAhi : SBhi;
      unsigned short* el = (s % 2 == 0) ? SAlo : SBlo;
      if (s < 7) {
        k4_fused<<<512, 256, 0, stream>>>(256, Mhi, Mlo,
                                          st[s].bh, st[s].bl, st[s].ph, st[s].pl,
                                          st[s].dh, st[s].dl, st[s].cf, Pacc,
                                          qh, ql, eh, el,
                                          trc + (size_t)s * 4, trc + (size_t)(s + 1) * 4);
      } else {
        k4_fused<<<256, 256, 0, stream>>>(0, Mhi, Mlo,
                                          Mhi, Mlo, Mhi, Mlo, TAhi, TAlo, 0.f, Pacc,
                                          qh, ql, eh, el,
                                          trc + (size_t)s * 4, trc + (size_t)(s + 1) * 4);
      }
      qh = eh; ql = el;
    }
    // NSQ=13 odd count starting at s=0 even -> final output in SA.
    k5a_extract<<<4, 256, 0, stream>>>(SAhi, SAlo, vbuf);
  }
  k5b_rayleigh<<<64, 256, 0, stream>>>(Scov, vbuf, dot);
  k6_compose<<<2048, 256, 0, stream>>>(Pacc, vbuf, dot, mu, weight, bias, Wbf, offv);
  k7_apply<<<2048, 256, 0, stream>>>(Wbf, hi, offv, out);
}